// Round 1
// baseline (111.959 us; speedup 1.0000x reference)
//
#include <hip/hip_runtime.h>

// Problem shape (from setup_inputs): B=128, S=32768, C=4.
// logits f32 [B,S,4], labels i32 [B,S], seg_marks i32 [B,S]; out: scalar f32 mean.

#define TOL 5
#define HALO 5
#define CHUNK 2048
#define NTHREADS 256

__device__ __forceinline__ float cls_weight(int lab) {
    // CLASS_WEIGHTS = {0.1, 0.1, 5.0, 5.0}
    return (lab >= 2) ? 5.0f : 0.1f;
}

// Kernel 0: per-row any(labels >= 2)
static __global__ void has_true_kernel(const int* __restrict__ labels, int S,
                                       int* __restrict__ has_true) {
    const int b = blockIdx.x;
    const int* row = labels + (size_t)b * S;
    int any = 0;
    for (int i = threadIdx.x; i < S; i += blockDim.x) {
        any |= (row[i] >= 2);
    }
    __shared__ int s_any;
    if (threadIdx.x == 0) s_any = 0;
    __syncthreads();
    if (__any(any) && (threadIdx.x & 63) == 0) atomicOr(&s_any, 1);
    __syncthreads();
    if (threadIdx.x == 0) has_true[b] = s_any;
}

// Main kernel: one block per (row, chunk). LDS-staged flags with +/-HALO halo.
static __global__ __launch_bounds__(NTHREADS) void
loss_kernel(const float* __restrict__ logits, const int* __restrict__ labels,
            const int* __restrict__ seg, const int* __restrict__ has_true,
            int S, double* __restrict__ sums) {
    const int chunks_per_row = S / CHUNK;
    const int b = blockIdx.x / chunks_per_row;
    const int chunk = blockIdx.x % chunks_per_row;
    const int base = chunk * CHUNK;

    __shared__ float s_loss[CHUNK];
    __shared__ unsigned char s_pred[CHUNK + 2 * HALO];
    __shared__ unsigned char s_true[CHUNK + 2 * HALO];
    __shared__ unsigned char s_seg[CHUNK + 2 * HALO];

    const float* lrow = logits + (size_t)b * S * 4;
    const int* labrow = labels + (size_t)b * S;
    const int* segrow = seg + (size_t)b * S;

    // Phase 1: compute flags (halo included) + base CE loss (in-chunk only).
    for (int i = threadIdx.x; i < CHUNK + 2 * HALO; i += NTHREADS) {
        const int pos = base - HALO + i;
        unsigned char p = 0, t = 0, sg = 0;
        if (pos >= 0 && pos < S) {
            const float4 lg = *reinterpret_cast<const float4*>(lrow + (size_t)pos * 4);
            // argmax, first-occurrence on ties (strict >)
            float mx = lg.x; int am = 0;
            if (lg.y > mx) { mx = lg.y; am = 1; }
            if (lg.z > mx) { mx = lg.z; am = 2; }
            if (lg.w > mx) { mx = lg.w; am = 3; }
            p = (am >= 2);
            const int lab = labrow[pos];
            t = (lab >= 2);
            sg = (segrow[pos] > 0);
            if ((unsigned)(i - HALO) < (unsigned)CHUNK) {
                const bool ignored = (lab == -100);
                const int sl = ignored ? 0 : lab;
                const float e0 = expf(lg.x - mx), e1 = expf(lg.y - mx);
                const float e2 = expf(lg.z - mx), e3 = expf(lg.w - mx);
                const float logz = mx + logf(e0 + e1 + e2 + e3);
                const float picked = (sl == 0) ? lg.x : (sl == 1) ? lg.y
                                   : (sl == 2) ? lg.z : lg.w;
                const float bl = ignored ? 0.0f : cls_weight(sl) * (logz - picked);
                s_loss[i - HALO] = bl;
            }
        }
        s_pred[i] = p;
        s_true[i] = t;
        s_seg[i] = sg;
    }
    __syncthreads();

    const int ht = has_true[b];
    float lsum = 0.0f, lcnt = 0.0f;

    // Phase 2: window adjustments + accumulate.
    for (int i = threadIdx.x; i < CHUNK; i += NTHREADS) {
        const int pos = base + i;
        const int li = i + HALO;
        const int lab = labrow[pos];
        const float valid = (lab == -100) ? 0.0f : 1.0f;

        const bool pred_sw = s_pred[li] != 0;
        const bool true_sw = s_true[li] != 0;

        int pn = 0, tn = 0;
#pragma unroll
        for (int d = -TOL; d <= TOL; ++d) {
            pn |= s_pred[li + d];
            tn |= s_true[li + d];
        }

        const int seg_pos   = s_seg[li];
        const int seg_prev1 = s_seg[li - 1];
        const int seg_prev2 = s_seg[li - 2];
        const int seg_next1 = s_seg[li + 1];

        float adj = 0.0f;
        if (pred_sw) {
            adj += 2.0f * (float)((seg_prev1 | seg_prev2) != 0)   // SEG_PENALTY
                 - 1.0f * (float)((seg_pos | seg_next1) != 0);    // SEG_REWARD
        }
        adj -= 2.0f * (float)(true_sw && pn);                      // PROX_REWARD
        adj += 1.5f * (float)(pred_sw && ht && !tn);               // FAR_PENALTY

        const float loss = s_loss[i] + adj;
        lsum += loss * valid;
        lcnt += valid;
    }

    // Block reduction: wave shuffle, then cross-wave in LDS (double).
#pragma unroll
    for (int off = 32; off > 0; off >>= 1) {
        lsum += __shfl_down(lsum, off);
        lcnt += __shfl_down(lcnt, off);
    }
    __shared__ double s_red[(NTHREADS / 64) * 2];
    const int wid = threadIdx.x >> 6;
    if ((threadIdx.x & 63) == 0) {
        s_red[wid * 2 + 0] = (double)lsum;
        s_red[wid * 2 + 1] = (double)lcnt;
    }
    __syncthreads();
    if (threadIdx.x == 0) {
        double a = 0.0, c = 0.0;
#pragma unroll
        for (int w = 0; w < NTHREADS / 64; ++w) {
            a += s_red[w * 2 + 0];
            c += s_red[w * 2 + 1];
        }
        atomicAdd(&sums[0], a);
        atomicAdd(&sums[1], c);
    }
}

static __global__ void finalize_kernel(const double* __restrict__ sums,
                                       float* __restrict__ out) {
    out[0] = (float)(sums[0] / sums[1]);
}

extern "C" void kernel_launch(void* const* d_in, const int* in_sizes, int n_in,
                              void* d_out, int out_size, void* d_ws, size_t ws_size,
                              hipStream_t stream) {
    const float* logits = (const float*)d_in[0];
    const int* labels   = (const int*)d_in[1];
    const int* seg      = (const int*)d_in[2];
    float* out          = (float*)d_out;

    const int B = 128;
    const int S = 32768;  // in_sizes[1] == B*S == 4194304; fixed problem shape

    // Workspace layout: [0..16): double sums[2]; [16..16+4*B): int has_true[B]
    double* sums  = (double*)d_ws;
    int* has_true = (int*)((char*)d_ws + 16);

    // Zero accumulators every call (ws is NOT re-poisoned between replays).
    hipMemsetAsync(d_ws, 0, 16, stream);

    has_true_kernel<<<B, 256, 0, stream>>>(labels, S, has_true);

    const int grid = B * (S / CHUNK);
    loss_kernel<<<grid, NTHREADS, 0, stream>>>(logits, labels, seg, has_true, S, sums);

    finalize_kernel<<<1, 1, 0, stream>>>(sums, out);
}

// Round 2
// 78.556 us; speedup vs baseline: 1.4252x; 1.4252x over previous
//
#include <hip/hip_runtime.h>

// B=128, S=32768, C=4. logits f32 [B,S,4], labels i32, seg i32 -> scalar f32.

#define TOL 5
#define NTHREADS 256
#define EPT 8                    // elements per thread
#define CHUNK (NTHREADS * EPT)   // 2048

#if __has_builtin(__builtin_amdgcn_exp2f)
#define EXP2F(x) __builtin_amdgcn_exp2f(x)
#else
#define EXP2F(x) exp2f(x)
#endif
#if __has_builtin(__builtin_amdgcn_logf)
#define LOG2F(x) __builtin_amdgcn_logf(x)
#else
#define LOG2F(x) log2f(x)
#endif

// OR over shifts 0..10: {0,1} -> {0..3} -> {0..7} -> {0..10}
__device__ __forceinline__ unsigned smear10(unsigned x) {
    x |= x << 1;
    x |= x << 2;
    x |= x << 4;
    x |= x << 3;
    return x;
}

static __global__ __launch_bounds__(NTHREADS) void
loss_kernel(const float4* __restrict__ logits, const int* __restrict__ labels,
            const int* __restrict__ seg, double* __restrict__ sum_g,
            int* __restrict__ vcnt_g, int* __restrict__ ht_g,
            int* __restrict__ far_g, int S) {
    const int chunks_per_row = S / CHUNK;            // 16
    const int b = blockIdx.x / chunks_per_row;
    const int chunk = blockIdx.x - b * chunks_per_row;
    const int base = chunk * CHUNK;
    const int t = threadIdx.x;

    __shared__ unsigned char s_pm[NTHREADS + 2];
    __shared__ unsigned char s_tm[NTHREADS + 2];
    __shared__ unsigned char s_sm[NTHREADS + 2];
    __shared__ int s_ht;
    __shared__ float s_fred[NTHREADS / 64];
    __shared__ int s_ired[NTHREADS / 64];

    if (t == 0) s_ht = 0;
    __syncthreads();

    const size_t rowoff = (size_t)b * S;
    const float4* lrow = logits + rowoff;
    const int* labrow = labels + rowoff;
    const int* segrow = seg + rowoff;

    const int p0 = base + t * EPT;

    // ---- Phase 1: vector loads (one 128B line of logits per thread) ----
    float4 lg[EPT];
#pragma unroll
    for (int j = 0; j < EPT; ++j) lg[j] = lrow[p0 + j];
    const int4 la0 = *reinterpret_cast<const int4*>(labrow + p0);
    const int4 la1 = *reinterpret_cast<const int4*>(labrow + p0 + 4);
    const int4 sg0 = *reinterpret_cast<const int4*>(segrow + p0);
    const int4 sg1 = *reinterpret_cast<const int4*>(segrow + p0 + 4);
    const int labv[8] = {la0.x, la0.y, la0.z, la0.w, la1.x, la1.y, la1.z, la1.w};
    const int segv[8] = {sg0.x, sg0.y, sg0.z, sg0.w, sg1.x, sg1.y, sg1.z, sg1.w};

    unsigned pm = 0, tm = 0, sm = 0, vm = 0;
    float ce = 0.0f;
#pragma unroll
    for (int j = 0; j < EPT; ++j) {
        const float a = lg[j].x, bb = lg[j].y, c = lg[j].z, d = lg[j].w;
        const float mab = fmaxf(a, bb), mcd = fmaxf(c, d);
        const float mx = fmaxf(mab, mcd);
        // argmax>=2  <=>  max(c,d) > max(a,b)  (first-occurrence tie rule)
        pm |= (unsigned)(mcd > mab) << j;
        const int lab = labv[j];
        tm |= (unsigned)(lab >= 2) << j;
        sm |= (unsigned)(segv[j] > 0) << j;
        const int ign = (lab == -100);
        vm |= (unsigned)(!ign) << j;
        const int sl = ign ? 0 : lab;
        const float L2E = 1.4426950408889634f;
        const float s = EXP2F((a - mx) * L2E) + EXP2F((bb - mx) * L2E) +
                        EXP2F((c - mx) * L2E) + EXP2F((d - mx) * L2E);
        const float picked = (sl < 2) ? (sl == 0 ? a : bb) : (sl == 2 ? c : d);
        const float w = (sl >= 2) ? 5.0f : 0.1f;
        const float l = w * (mx - picked + 0.69314718055994531f * LOG2F(s));
        ce += ign ? 0.0f : l;
    }
    s_pm[t + 1] = (unsigned char)pm;
    s_tm[t + 1] = (unsigned char)tm;
    s_sm[t + 1] = (unsigned char)sm;
    if (tm) s_ht = 1;  // benign race: all writers store 1

    // Halo bytes (8 positions left of chunk, 8 right), zero outside the row.
    if (t < 2) {
        const int hp0 = (t == 0) ? (base - 8) : (base + CHUNK);
        unsigned hp = 0, htr = 0, hsg = 0;
#pragma unroll
        for (int j = 0; j < 8; ++j) {
            const int pos = hp0 + j;
            if (pos >= 0 && pos < S) {
                const float4 g = lrow[pos];
                const float mab = fmaxf(g.x, g.y), mcd = fmaxf(g.z, g.w);
                hp |= (unsigned)(mcd > mab) << j;
                htr |= (unsigned)(labrow[pos] >= 2) << j;
                hsg |= (unsigned)(segrow[pos] > 0) << j;
            }
        }
        const int idx = (t == 0) ? 0 : (NTHREADS + 1);
        s_pm[idx] = (unsigned char)hp;
        s_tm[idx] = (unsigned char)htr;
        s_sm[idx] = (unsigned char)hsg;
    }
    __syncthreads();

    // ---- Phase 2: bitmask window math ----
    // x bit k (k=0..23) = flag(p0 - 8 + k)
    const unsigned xp = (unsigned)s_pm[t] | ((unsigned)s_pm[t + 1] << 8) |
                        ((unsigned)s_pm[t + 2] << 16);
    const unsigned xt = (unsigned)s_tm[t] | ((unsigned)s_tm[t + 1] << 8) |
                        ((unsigned)s_tm[t + 2] << 16);
    const unsigned xz = (unsigned)s_sm[t] | ((unsigned)s_sm[t + 1] << 8) |
                        ((unsigned)s_sm[t + 2] << 16);

    const unsigned pn = (smear10(xp) >> 13) & 0xFFu;          // any pred in +/-5
    const unsigned tn = (smear10(xt) >> 13) & 0xFFu;          // any true in +/-5
    const unsigned pc = ((xz >> 6) | (xz >> 7)) & 0xFFu;      // seg[p-1]|seg[p-2]
    const unsigned rc = ((xz >> 8) | (xz >> 9)) & 0xFFu;      // seg[p]|seg[p+1]

    const int npc = __popc(pm & pc & vm);    // SEG_PENALTY hits
    const int nrc = __popc(pm & rc & vm);    // SEG_REWARD hits
    const int npr = __popc(tm & pn & vm);    // PROX_REWARD hits
    const int nfar = __popc(pm & ~tn & vm);  // FAR candidates (x ht[b] later)
    const int nval = __popc(vm);

    float lsum = ce + (float)(2 * npc - nrc - 2 * npr);
    int packed = nval | (nfar << 16);

#pragma unroll
    for (int off = 32; off > 0; off >>= 1) {
        lsum += __shfl_down(lsum, off);
        packed += __shfl_down(packed, off);
    }
    const int wid = t >> 6;
    if ((t & 63) == 0) { s_fred[wid] = lsum; s_ired[wid] = packed; }
    __syncthreads();
    if (t == 0) {
        float fs = 0.0f;
        int ps = 0;
#pragma unroll
        for (int w = 0; w < NTHREADS / 64; ++w) { fs += s_fred[w]; ps += s_ired[w]; }
        atomicAdd(sum_g, (double)fs);
        atomicAdd(vcnt_g, ps & 0xFFFF);
        atomicAdd(&far_g[b], ps >> 16);
        if (s_ht) atomicOr(&ht_g[b], 1);
    }
}

static __global__ void finalize_kernel(const double* __restrict__ sum_g,
                                       const int* __restrict__ vcnt_g,
                                       const int* __restrict__ ht_g,
                                       const int* __restrict__ far_g,
                                       float* __restrict__ out) {
    const int t = threadIdx.x;  // 128 threads
    int f = ht_g[t] ? far_g[t] : 0;
#pragma unroll
    for (int off = 32; off > 0; off >>= 1) f += __shfl_down(f, off);
    __shared__ int s_f[2];
    if ((t & 63) == 0) s_f[t >> 6] = f;
    __syncthreads();
    if (t == 0) {
        const double tot = sum_g[0] + 1.5 * (double)(s_f[0] + s_f[1]);
        out[0] = (float)(tot / (double)vcnt_g[0]);
    }
}

extern "C" void kernel_launch(void* const* d_in, const int* in_sizes, int n_in,
                              void* d_out, int out_size, void* d_ws, size_t ws_size,
                              hipStream_t stream) {
    const float4* logits = (const float4*)d_in[0];
    const int* labels = (const int*)d_in[1];
    const int* seg = (const int*)d_in[2];
    float* out = (float*)d_out;

    const int B = 128;
    const int S = 32768;

    // ws layout: [0,8) double sum; [8,12) int vcnt; [16,16+512) int ht[128];
    //            [528,528+512) int far[128]
    double* sum_g = (double*)d_ws;
    int* vcnt_g = (int*)((char*)d_ws + 8);
    int* ht_g = (int*)((char*)d_ws + 16);
    int* far_g = (int*)((char*)d_ws + 528);

    hipMemsetAsync(d_ws, 0, 1040, stream);

    const int grid = B * (S / CHUNK);  // 2048
    loss_kernel<<<grid, NTHREADS, 0, stream>>>(logits, labels, seg, sum_g,
                                               vcnt_g, ht_g, far_g, S);
    finalize_kernel<<<1, 128, 0, stream>>>(sum_g, vcnt_g, ht_g, far_g, out);
}